// Round 5
// baseline (464.071 us; speedup 1.0000x reference)
//
#include <hip/hip_runtime.h>
#include <hip/hip_bf16.h>

// y[m, p*32+q] = sum_{r,s} x[m, r*32+s] * W2[p,r] * W1[q,s] + bias[p*32+q]
//   == (W2 · X_m · W1^T)[p,q],  X_m = reshape(x[m], 32, 32)
//
// One wave per row m. Stage 1: T = X·W1^T (2x mfma_32x32x16_bf16).
// Stage 2: Y = W2·T (round-0 orientation -> 128B-coalesced scalar stores);
// T B-fragment rebuilt in-register via v_cvt_pk_bf16_f32 + permlane32_swap.
// This round: all f32->bf16 via the cvt_pk intrinsic (16 VALU/row instead of
// ~100 for bit-twiddled f2bf), non-temporal x loads + out stores (pure
// streaming, keep L2 clean), __launch_bounds__(256,4) to pin <=128 VGPR.

typedef short bf16x8 __attribute__((ext_vector_type(8)));   // 8 bf16 = 4 VGPRs
typedef float f32x16 __attribute__((ext_vector_type(16)));  // C/D acc
typedef float f32x4  __attribute__((ext_vector_type(4)));
typedef unsigned uint32x2 __attribute__((ext_vector_type(2)));
typedef unsigned uint32x4 __attribute__((ext_vector_type(4)));

#define MFMA32(A, B, C) __builtin_amdgcn_mfma_f32_32x32x16_bf16((A), (B), (C), 0, 0, 0)

// two f32 -> one dword of two bf16 (RNE), low = lo, high = hi.
// Intrinsic form (v_cvt_pk_bf16_f32) so the scheduler can move it freely.
__device__ __forceinline__ unsigned pk2(float lo, float hi) {
    float2 f; f.x = lo; f.y = hi;
    __hip_bfloat162 b = __float22bfloat162_rn(f);
    unsigned r;
    __builtin_memcpy(&r, &b, 4);   // bit move; type not trivially copyable
    return r;
}

// fp32 -> bf16 RNE (loop-invariant weight fragments only, once per kernel)
__device__ __forceinline__ short f2bf(float f) {
    unsigned u = __builtin_bit_cast(unsigned, f);
    u = (u + 0x7fffu + ((u >> 16) & 1u)) >> 16;
    return (short)u;
}

constexpr int M_TOTAL = 8 * 8192;   // 65536 rows of 1024
constexpr int BLOCKS  = 2048;
constexpr int TPB     = 256;        // 4 waves/block
constexpr int NWAVES  = BLOCKS * (TPB / 64);   // 8192 waves
constexpr int RPW     = M_TOTAL / NWAVES;      // 8 rows/wave

__global__ __launch_bounds__(TPB, 4) void kron_mlp_kernel(
    const float* __restrict__ x,    // (65536, 1024)
    const float* __restrict__ w1,   // (32, 32): W1[q][s]
    const float* __restrict__ w2,   // (32, 32): W2[p][r]
    const float* __restrict__ bias, // (1024,)
    float* __restrict__ out)        // (65536, 1024)
{
    const int tid  = threadIdx.x;
    const int wid  = tid >> 6;
    const int lane = tid & 63;
    const int c    = lane & 31;   // A row / B col index
    const int h    = lane >> 5;   // half-wave k-range selector

    // ---- loop-invariant fragments ----
    // Stage-1 B (W1^T): element[k=8h+j][n=c] = W1[c][8h+j]   (b1: +16)
    // Stage-2 A (W2):   element[m=c][k=8h+j] = W2[c][8h+j]   (a1: +16)
    bf16x8 w1b0, w1b1, w2a0, w2a1;
    {
        const float* p1 = w1 + c * 32 + 8 * h;
        const float* p2 = w2 + c * 32 + 8 * h;
        #pragma unroll
        for (int j = 0; j < 8; ++j) {
            w1b0[j] = f2bf(p1[j]);  w1b1[j] = f2bf(p1[16 + j]);
            w2a0[j] = f2bf(p2[j]);  w2a1[j] = f2bf(p2[16 + j]);
        }
    }

    // Stage-2 C-init = bias. C/D: col=q=c, row=p=(reg&3)+8*(reg>>2)+4h,
    // y-index = p*32+q -> reg 4g+i corresponds to bias[(i+8g+4h)*32 + c].
    f32x16 yinit;
    #pragma unroll
    for (int g = 0; g < 4; ++g)
        #pragma unroll
        for (int i = 0; i < 4; ++i)
            yinit[4 * g + i] = bias[(i + 8 * g + 4 * h) * 32 + c];

    const int    gwave   = blockIdx.x * (TPB / 64) + wid;
    const size_t RSTRIDE = (size_t)NWAVES * 1024;   // row k -> row k+1 (per wave)

    const float* xp = x   + (size_t)gwave * 1024 + c * 32 + 8 * h;
    float*       op = out + (size_t)gwave * 1024;

    auto run_row = [&](const f32x4& xa, const f32x4& xb,
                       const f32x4& xc, const f32x4& xd, float* o) {
        // Stage-1 A (X_m): element[row=c][k=8h+j] = x[c*32 + 8h + j] (a1: +16)
        // Packed via cvt_pk: dword j = {elem 2j (lo), elem 2j+1 (hi)}.
        uint32x4 ua = { pk2(xa[0], xa[1]), pk2(xa[2], xa[3]),
                        pk2(xb[0], xb[1]), pk2(xb[2], xb[3]) };
        uint32x4 ub = { pk2(xc[0], xc[1]), pk2(xc[2], xc[3]),
                        pk2(xd[0], xd[1]), pk2(xd[2], xd[3]) };

        // Stage 1: T = X · W1^T  (K=32 as two K=16 MFMAs)
        f32x16 t = {};
        t = MFMA32(__builtin_bit_cast(bf16x8, ua), w1b0, t);
        t = MFMA32(__builtin_bit_cast(bf16x8, ub), w1b1, t);

        // In-register re-layout: lane (c,h') reg r holds T[(r&3)+8*(r>>2)+4h'][c].
        // Stage-2 B fragment needs tb0[j]=T[8h+j][c], tb1[j]=T[16+8h+j][c].
        // permlane32_swap(A,B): new_A = {A.lo31, B.lo31}, new_B = {A.hi31, B.hi31}
        // (semantics HW-verified: refcheck passed rounds 1/3/4).
        uint32x2 r0 = __builtin_amdgcn_permlane32_swap(pk2(t[0],  t[1]),  pk2(t[4],  t[5]),  false, false);
        uint32x2 r1 = __builtin_amdgcn_permlane32_swap(pk2(t[2],  t[3]),  pk2(t[6],  t[7]),  false, false);
        uint32x2 r2 = __builtin_amdgcn_permlane32_swap(pk2(t[8],  t[9]),  pk2(t[12], t[13]), false, false);
        uint32x2 r3 = __builtin_amdgcn_permlane32_swap(pk2(t[10], t[11]), pk2(t[14], t[15]), false, false);
        uint32x4 utb0 = { r0[0], r1[0], r0[1], r1[1] };
        uint32x4 utb1 = { r2[0], r3[0], r2[1], r3[1] };

        // Stage 2: Y = W2 · T, C init = bias
        f32x16 yv = yinit;
        yv = MFMA32(w2a0, __builtin_bit_cast(bf16x8, utb0), yv);
        yv = MFMA32(w2a1, __builtin_bit_cast(bf16x8, utb1), yv);

        // Epilogue: reg 4g+i -> out[(i+8g+4h)*32 + c]; each store instruction
        // covers q=0..31 contiguous dwords (full 128B lines) -> coalesced.
        // Non-temporal: pure streaming output, keep L2 for the read stream.
        #pragma unroll
        for (int g = 0; g < 4; ++g)
            #pragma unroll
            for (int i = 0; i < 4; ++i)
                __builtin_nontemporal_store(yv[4 * g + i],
                                            o + (i + 8 * g + 4 * h) * 32 + c);
    };

    // x-row fragment loads: 4x float4 per lane at c*128B + h*32B (+0,+16,+64,+80)
    // Non-temporal: x is streamed exactly once.
    f32x4 xa = __builtin_nontemporal_load((const f32x4*)(xp + 0));
    f32x4 xb = __builtin_nontemporal_load((const f32x4*)(xp + 4));
    f32x4 xc = __builtin_nontemporal_load((const f32x4*)(xp + 16));
    f32x4 xd = __builtin_nontemporal_load((const f32x4*)(xp + 20));

    #pragma unroll 1
    for (int it = 0; it < RPW - 1; ++it) {
        const float* np = xp + RSTRIDE;          // prefetch next row first
        f32x4 na = __builtin_nontemporal_load((const f32x4*)(np + 0));
        f32x4 nb = __builtin_nontemporal_load((const f32x4*)(np + 4));
        f32x4 nc = __builtin_nontemporal_load((const f32x4*)(np + 16));
        f32x4 nd = __builtin_nontemporal_load((const f32x4*)(np + 20));
        run_row(xa, xb, xc, xd, op);
        xa = na; xb = nb; xc = nc; xd = nd;
        xp = np; op += RSTRIDE;
    }
    run_row(xa, xb, xc, xd, op);
}

extern "C" void kernel_launch(void* const* d_in, const int* in_sizes, int n_in,
                              void* d_out, int out_size, void* d_ws, size_t ws_size,
                              hipStream_t stream) {
    const float* x    = (const float*)d_in[0];
    const float* w1   = (const float*)d_in[1];
    const float* w2   = (const float*)d_in[2];
    const float* bias = (const float*)d_in[3];
    float* out        = (float*)d_out;
    kron_mlp_kernel<<<dim3(BLOCKS), dim3(TPB), 0, stream>>>(x, w1, w2, bias, out);
}